// Round 1
// baseline (3102.849 us; speedup 1.0000x reference)
//
#include <hip/hip_runtime.h>
#include <hip/hip_bf16.h>

#define N_NODES 100000
#define N_EDGES 1600000
#define IN_DIM  128
#define HID     256
#define OUT_DIM 128
#define BN_EPS  1e-5f

typedef unsigned int u32;
typedef unsigned short u16;

__device__ __forceinline__ float bf2f(u16 h) {
    return __uint_as_float(((u32)h) << 16);
}
__device__ __forceinline__ u16 f2bf(float f) {
    u32 u = __float_as_uint(f);
    u32 r = (u + 0x7fffu + ((u >> 16) & 1u)) >> 16;   // round-to-nearest-even
    return (u16)r;
}
__device__ __forceinline__ u32 pack2(float a, float b) {
    return (u32)f2bf(a) | ((u32)f2bf(b) << 16);
}

// ---------------- aggr = (1+eps)*x ----------------
__global__ __launch_bounds__(256) void k_init(const float* __restrict__ x,
                                              const float* __restrict__ epsp,
                                              float* __restrict__ aggr) {
    const float s = 1.0f + epsp[0];
    int i = blockIdx.x * 256 + threadIdx.x;
    const int total = N_NODES * IN_DIM / 4;
    if (i < total) {
        float4 v = ((const float4*)x)[i];
        v.x *= s; v.y *= s; v.z *= s; v.w *= s;
        ((float4*)aggr)[i] = v;
    }
}

// ---------------- aggr[dst] += x[src]  (atomic scatter) ----------------
__global__ __launch_bounds__(256) void k_scatter(const float* __restrict__ x,
                                                 const int* __restrict__ ei,
                                                 float* __restrict__ aggr) {
    int t = blockIdx.x * 256 + threadIdx.x;   // one thread per (edge, 16B chunk)
    int e = t >> 5;
    if (e >= N_EDGES) return;
    int c = t & 31;
    int src = ei[e];
    int dst = ei[N_EDGES + e];
    float4 v = ((const float4*)x)[src * 32 + c];
    float* out = aggr + (size_t)dst * IN_DIM + (size_t)c * 4;
    atomicAdd(out + 0, v.x);
    atomicAdd(out + 1, v.y);
    atomicAdd(out + 2, v.z);
    atomicAdd(out + 3, v.w);
}

// ---------------- h1 = aggr @ W1 + b1 (bf16 store), col sum/sumsq stats ----------------
__global__ __launch_bounds__(512) void k_gemm1(const float* __restrict__ aggr,
                                               const float* __restrict__ W1,
                                               const float* __restrict__ b1,
                                               u32* __restrict__ h1,        // bf16 pairs
                                               float* __restrict__ gstats)  // [512]: sum, sumsq
{
    __shared__ u16 w1s[IN_DIM * HID];      // 64 KB bf16 weights
    __shared__ u16 rbT[IN_DIM * 36];       // rows transposed, [k][r(0..31)+pad]
    __shared__ float slds[HID * 2];        // block stats reduce

    const int tid = threadIdx.x;
    const int lane = tid & 63;
    const int w = tid >> 6;                // wave 0..7

    for (int i = tid; i < IN_DIM * HID; i += 512)
        w1s[i] = f2bf(W1[i]);

    const float4 b1v = ((const float4*)b1)[lane];   // cols 4*lane .. 4*lane+3

    float csum[4] = {0.f,0.f,0.f,0.f}, csq[4] = {0.f,0.f,0.f,0.f};

    const int ngrp = N_NODES / 32;   // 3125 (exact)
    for (int g = blockIdx.x; g < ngrp; g += gridDim.x) {
        const int base = g * 32;
        __syncthreads();   // prev iter readers done; w1s loads done (1st iter)
        // stage 32 rows of aggr, transposed bf16
        #pragma unroll
        for (int j = 0; j < 2; ++j) {
            int idx = tid + j * 512;      // 0..1023
            int r = idx >> 5;             // 0..31
            int cq = idx & 31;            // float4 within row
            float4 v = ((const float4*)aggr)[(base + r) * 32 + cq];
            int c = 4 * cq;
            rbT[(c + 0) * 36 + r] = f2bf(v.x);
            rbT[(c + 1) * 36 + r] = f2bf(v.y);
            rbT[(c + 2) * 36 + r] = f2bf(v.z);
            rbT[(c + 3) * 36 + r] = f2bf(v.w);
        }
        __syncthreads();

        float acc[4][4];
        #pragma unroll
        for (int i = 0; i < 4; ++i)
            #pragma unroll
            for (int j = 0; j < 4; ++j) acc[i][j] = 0.f;

        const u32* w1r = (const u32*)w1s;   // 128 u32 per k-row
        const u32* rbr = (const u32*)rbT;   // 18 u32 per k-row
        #pragma unroll 4
        for (int k = 0; k < IN_DIM; ++k) {
            u32 wa = w1r[k * 128 + 2 * lane];
            u32 wb = w1r[k * 128 + 2 * lane + 1];
            u32 ra = rbr[k * 18 + 2 * w];
            u32 rb = rbr[k * 18 + 2 * w + 1];
            float wc0 = bf2f((u16)wa), wc1 = bf2f((u16)(wa >> 16));
            float wc2 = bf2f((u16)wb), wc3 = bf2f((u16)(wb >> 16));
            float r0 = bf2f((u16)ra), r1 = bf2f((u16)(ra >> 16));
            float r2 = bf2f((u16)rb), r3 = bf2f((u16)(rb >> 16));
            acc[0][0] = fmaf(r0, wc0, acc[0][0]); acc[0][1] = fmaf(r0, wc1, acc[0][1]);
            acc[0][2] = fmaf(r0, wc2, acc[0][2]); acc[0][3] = fmaf(r0, wc3, acc[0][3]);
            acc[1][0] = fmaf(r1, wc0, acc[1][0]); acc[1][1] = fmaf(r1, wc1, acc[1][1]);
            acc[1][2] = fmaf(r1, wc2, acc[1][2]); acc[1][3] = fmaf(r1, wc3, acc[1][3]);
            acc[2][0] = fmaf(r2, wc0, acc[2][0]); acc[2][1] = fmaf(r2, wc1, acc[2][1]);
            acc[2][2] = fmaf(r2, wc2, acc[2][2]); acc[2][3] = fmaf(r2, wc3, acc[2][3]);
            acc[3][0] = fmaf(r3, wc0, acc[3][0]); acc[3][1] = fmaf(r3, wc1, acc[3][1]);
            acc[3][2] = fmaf(r3, wc2, acc[3][2]); acc[3][3] = fmaf(r3, wc3, acc[3][3]);
        }

        #pragma unroll
        for (int i = 0; i < 4; ++i) {
            int row = base + 4 * w + i;
            float h0 = acc[i][0] + b1v.x;
            float h1f = acc[i][1] + b1v.y;
            float h2f = acc[i][2] + b1v.z;
            float h3f = acc[i][3] + b1v.w;
            csum[0] += h0;  csum[1] += h1f;  csum[2] += h2f;  csum[3] += h3f;
            csq[0] += h0 * h0; csq[1] += h1f * h1f; csq[2] += h2f * h2f; csq[3] += h3f * h3f;
            h1[row * 128 + 2 * lane]     = pack2(h0, h1f);
            h1[row * 128 + 2 * lane + 1] = pack2(h2f, h3f);
        }
    }

    __syncthreads();
    slds[tid] = 0.f;                       // tid 0..511 covers 512 slots
    __syncthreads();
    #pragma unroll
    for (int j = 0; j < 4; ++j) {
        atomicAdd(&slds[4 * lane + j], csum[j]);
        atomicAdd(&slds[HID + 4 * lane + j], csq[j]);
    }
    __syncthreads();
    atomicAdd(&gstats[tid], slds[tid]);
}

// ---------------- h2 = relu(bn1(h1)) @ W2 + b2 (f32 -> d_out), stats2 ----------------
__global__ __launch_bounds__(512) void k_gemm2(const u32* __restrict__ h1,
                                               const float* __restrict__ W2,
                                               const float* __restrict__ b2,
                                               const float* __restrict__ g1,
                                               const float* __restrict__ beta1,
                                               const float* __restrict__ gstats,   // [512]
                                               float* __restrict__ out,            // pre-BN h2
                                               float* __restrict__ gstats2)        // [256]
{
    __shared__ u16 w2s[HID * OUT_DIM];     // 64 KB
    __shared__ u16 rbT[HID * 36];          // 18.4 KB
    __shared__ float a1s[HID], b1s[HID];
    __shared__ float slds[OUT_DIM * 2];

    const int tid = threadIdx.x;
    const int lane = tid & 63;
    const int w = tid >> 6;

    for (int i = tid; i < HID * OUT_DIM; i += 512)
        w2s[i] = f2bf(W2[i]);
    if (tid < HID) {
        float s = gstats[tid], sq = gstats[HID + tid];
        float mu = s * (1.0f / N_NODES);
        float var = sq * (1.0f / N_NODES) - mu * mu;
        float inv = rsqrtf(var + BN_EPS);
        float a = g1[tid] * inv;
        a1s[tid] = a;
        b1s[tid] = beta1[tid] - mu * a;
    }

    const float2 b2v = ((const float2*)b2)[lane];   // cols 2*lane, 2*lane+1
    float csum[2] = {0.f,0.f}, csq[2] = {0.f,0.f};

    const int ngrp = N_NODES / 32;
    for (int g = blockIdx.x; g < ngrp; g += gridDim.x) {
        const int base = g * 32;
        __syncthreads();
        // stage 32 rows of h1 with BN1+ReLU applied, transposed bf16
        #pragma unroll
        for (int j = 0; j < 4; ++j) {
            int idx = tid + j * 512;       // 0..2047
            int r = idx >> 6;              // 0..31 (64 uint2 per row)
            int cq = idx & 63;
            uint2 v = ((const uint2*)h1)[(base + r) * 64 + cq];
            int c = 4 * cq;
            float f0 = fmaxf(bf2f((u16)v.x)         * a1s[c + 0] + b1s[c + 0], 0.f);
            float f1 = fmaxf(bf2f((u16)(v.x >> 16)) * a1s[c + 1] + b1s[c + 1], 0.f);
            float f2 = fmaxf(bf2f((u16)v.y)         * a1s[c + 2] + b1s[c + 2], 0.f);
            float f3 = fmaxf(bf2f((u16)(v.y >> 16)) * a1s[c + 3] + b1s[c + 3], 0.f);
            rbT[(c + 0) * 36 + r] = f2bf(f0);
            rbT[(c + 1) * 36 + r] = f2bf(f1);
            rbT[(c + 2) * 36 + r] = f2bf(f2);
            rbT[(c + 3) * 36 + r] = f2bf(f3);
        }
        __syncthreads();

        float acc[4][2] = {{0.f,0.f},{0.f,0.f},{0.f,0.f},{0.f,0.f}};
        const u32* w2r = (const u32*)w2s;   // 64 u32 per k-row
        const u32* rbr = (const u32*)rbT;   // 18 u32 per k-row
        #pragma unroll 4
        for (int k = 0; k < HID; ++k) {
            u32 wv = w2r[k * 64 + lane];
            u32 ra = rbr[k * 18 + 2 * w];
            u32 rb = rbr[k * 18 + 2 * w + 1];
            float wc0 = bf2f((u16)wv), wc1 = bf2f((u16)(wv >> 16));
            float r0 = bf2f((u16)ra), r1 = bf2f((u16)(ra >> 16));
            float r2 = bf2f((u16)rb), r3 = bf2f((u16)(rb >> 16));
            acc[0][0] = fmaf(r0, wc0, acc[0][0]); acc[0][1] = fmaf(r0, wc1, acc[0][1]);
            acc[1][0] = fmaf(r1, wc0, acc[1][0]); acc[1][1] = fmaf(r1, wc1, acc[1][1]);
            acc[2][0] = fmaf(r2, wc0, acc[2][0]); acc[2][1] = fmaf(r2, wc1, acc[2][1]);
            acc[3][0] = fmaf(r3, wc0, acc[3][0]); acc[3][1] = fmaf(r3, wc1, acc[3][1]);
        }

        #pragma unroll
        for (int i = 0; i < 4; ++i) {
            int row = base + 4 * w + i;
            float h0 = acc[i][0] + b2v.x;
            float h1f = acc[i][1] + b2v.y;
            csum[0] += h0;  csum[1] += h1f;
            csq[0] += h0 * h0; csq[1] += h1f * h1f;
            ((float2*)out)[row * 64 + lane] = make_float2(h0, h1f);
        }
    }

    __syncthreads();
    if (tid < OUT_DIM * 2) slds[tid] = 0.f;
    __syncthreads();
    atomicAdd(&slds[2 * lane + 0], csum[0]);
    atomicAdd(&slds[2 * lane + 1], csum[1]);
    atomicAdd(&slds[OUT_DIM + 2 * lane + 0], csq[0]);
    atomicAdd(&slds[OUT_DIM + 2 * lane + 1], csq[1]);
    __syncthreads();
    if (tid < OUT_DIM * 2) atomicAdd(&gstats2[tid], slds[tid]);
}

// ---------------- out = relu(bn2(h2)) in-place ----------------
__global__ __launch_bounds__(256) void k_bn2(float* __restrict__ out,
                                             const float* __restrict__ gstats2,
                                             const float* __restrict__ g2,
                                             const float* __restrict__ beta2) {
    int i = blockIdx.x * 256 + threadIdx.x;      // float4 index
    const int total = N_NODES * OUT_DIM / 4;
    if (i >= total) return;
    float4 v = ((float4*)out)[i];
    int c = (i & 31) * 4;
    float vv[4] = {v.x, v.y, v.z, v.w};
    float res[4];
    #pragma unroll
    for (int j = 0; j < 4; ++j) {
        float s = gstats2[c + j], sq = gstats2[OUT_DIM + c + j];
        float mu = s * (1.0f / N_NODES);
        float var = sq * (1.0f / N_NODES) - mu * mu;
        float inv = rsqrtf(var + BN_EPS);
        float a = g2[c + j] * inv;
        float b = beta2[c + j] - mu * a;
        res[j] = fmaxf(vv[j] * a + b, 0.f);
    }
    ((float4*)out)[i] = make_float4(res[0], res[1], res[2], res[3]);
}

extern "C" void kernel_launch(void* const* d_in, const int* in_sizes, int n_in,
                              void* d_out, int out_size, void* d_ws, size_t ws_size,
                              hipStream_t stream) {
    const float* x     = (const float*)d_in[0];
    const int*   ei    = (const int*)d_in[1];
    const float* epsp  = (const float*)d_in[2];
    const float* W1    = (const float*)d_in[3];
    const float* b1    = (const float*)d_in[4];
    const float* g1    = (const float*)d_in[5];
    const float* beta1 = (const float*)d_in[6];
    const float* W2    = (const float*)d_in[7];
    const float* b2    = (const float*)d_in[8];
    const float* g2    = (const float*)d_in[9];
    const float* beta2 = (const float*)d_in[10];

    char* ws = (char*)d_ws;
    float* aggr    = (float*)ws;                    // 51.2 MB  f32 [N][128]
    u32*   h1      = (u32*)(ws + 51200000);         // 51.2 MB  bf16 [N][256]
    float* gstats  = (float*)(ws + 102400000);      // 512 f32 (sum1, sumsq1)
    float* gstats2 = gstats + 512;                  // 256 f32 (sum2, sumsq2)
    float* out = (float*)d_out;

    hipMemsetAsync(gstats, 0, 768 * sizeof(float), stream);

    k_init<<<(N_NODES * IN_DIM / 4 + 255) / 256, 256, 0, stream>>>(x, epsp, aggr);
    k_scatter<<<(N_EDGES * 32) / 256, 256, 0, stream>>>(x, ei, aggr);
    k_gemm1<<<1024, 512, 0, stream>>>(aggr, W1, b1, h1, gstats);
    k_gemm2<<<1024, 512, 0, stream>>>(h1, W2, b2, g1, beta1, gstats, out, gstats2);
    k_bn2<<<(N_NODES * OUT_DIM / 4 + 255) / 256, 256, 0, stream>>>(out, gstats2, g2, beta2);
}

// Round 2
// 703.166 us; speedup vs baseline: 4.4127x; 4.4127x over previous
//
#include <hip/hip_runtime.h>
#include <hip/hip_bf16.h>

#define N_NODES 100000
#define N_EDGES 1600000
#define IN_DIM  128
#define HID     256
#define OUT_DIM 128
#define BN_EPS  1e-5f

typedef unsigned int u32;
typedef unsigned short u16;

__device__ __forceinline__ float bf2f(u16 h) {
    return __uint_as_float(((u32)h) << 16);
}
__device__ __forceinline__ u16 f2bf(float f) {
    u32 u = __float_as_uint(f);
    u32 r = (u + 0x7fffu + ((u >> 16) & 1u)) >> 16;   // round-to-nearest-even
    return (u16)r;
}
__device__ __forceinline__ u32 pack2(float a, float b) {
    return (u32)f2bf(a) | ((u32)f2bf(b) << 16);
}

// ---------------- CSR build: degree histogram ----------------
__global__ __launch_bounds__(256) void k_hist(const int* __restrict__ ei,
                                              int* __restrict__ counts) {
    int e = blockIdx.x * 256 + threadIdx.x;
    if (e < N_EDGES) atomicAdd(&counts[ei[N_EDGES + e]], 1);
}

// ---------------- scan phase A: per-block sums (1024 elems/block) ----------------
__global__ __launch_bounds__(1024) void k_bsum(const int* __restrict__ counts,
                                               int* __restrict__ bsum) {
    __shared__ int s[1024];
    int i = blockIdx.x * 1024 + threadIdx.x;
    s[threadIdx.x] = (i < N_NODES) ? counts[i] : 0;
    __syncthreads();
    for (int d = 512; d > 0; d >>= 1) {
        if (threadIdx.x < d) s[threadIdx.x] += s[threadIdx.x + d];
        __syncthreads();
    }
    if (threadIdx.x == 0) bsum[blockIdx.x] = s[0];
}

// ---------------- scan phase B: exclusive scan of 98 block sums ----------------
__global__ __launch_bounds__(128) void k_bscan(int* __restrict__ bsum, int nblk) {
    __shared__ int s[128];
    int v = (threadIdx.x < nblk) ? bsum[threadIdx.x] : 0;
    s[threadIdx.x] = v;
    __syncthreads();
    for (int d = 1; d < 128; d <<= 1) {
        int t = (threadIdx.x >= d) ? s[threadIdx.x - d] : 0;
        __syncthreads();
        s[threadIdx.x] += t;
        __syncthreads();
    }
    if (threadIdx.x < nblk) bsum[threadIdx.x] = s[threadIdx.x] - v;  // exclusive
}

// ---------------- scan phase C: write offsets + cursor ----------------
__global__ __launch_bounds__(1024) void k_offsets(const int* __restrict__ counts,
                                                  const int* __restrict__ bsum,
                                                  int* __restrict__ offsets,
                                                  int* __restrict__ cursor) {
    __shared__ int s[1024];
    int i = blockIdx.x * 1024 + threadIdx.x;
    int v = (i < N_NODES) ? counts[i] : 0;
    s[threadIdx.x] = v;
    __syncthreads();
    for (int d = 1; d < 1024; d <<= 1) {
        int t = (threadIdx.x >= d) ? s[threadIdx.x - d] : 0;
        __syncthreads();
        s[threadIdx.x] += t;
        __syncthreads();
    }
    int carry = bsum[blockIdx.x];
    if (i < N_NODES) {
        int excl = carry + s[threadIdx.x] - v;
        offsets[i] = excl;
        cursor[i] = excl;
        if (i == N_NODES - 1) offsets[N_NODES] = carry + s[threadIdx.x];
    }
}

// ---------------- CSR fill: srcs grouped by dst ----------------
__global__ __launch_bounds__(256) void k_fill(const int* __restrict__ ei,
                                              int* __restrict__ cursor,
                                              int* __restrict__ srcs) {
    int e = blockIdx.x * 256 + threadIdx.x;
    if (e >= N_EDGES) return;
    int dst = ei[N_EDGES + e];
    int pos = atomicAdd(&cursor[dst], 1);
    srcs[pos] = ei[e];
}

// ---------------- gather-aggregate: aggr_bf16[n] = (1+eps)*x[n] + sum x[srcs] ----------------
__global__ __launch_bounds__(256) void k_aggregate(const float* __restrict__ x,
                                                   const int* __restrict__ srcs,
                                                   const int* __restrict__ offsets,
                                                   const float* __restrict__ epsp,
                                                   u32* __restrict__ aggrb) {
    int node = blockIdx.x * 4 + (threadIdx.x >> 6);   // one wave per node
    int lane = threadIdx.x & 63;
    int c = lane & 31;        // float4 chunk within row (32 chunks = 128 floats)
    int h = lane >> 5;        // half-wave: splits edge list even/odd
    float4 acc = make_float4(0.f, 0.f, 0.f, 0.f);
    if (h == 0) {
        float sc = 1.0f + epsp[0];
        float4 v = ((const float4*)x)[node * 32 + c];
        acc.x = v.x * sc; acc.y = v.y * sc; acc.z = v.z * sc; acc.w = v.w * sc;
    }
    int beg = offsets[node], end = offsets[node + 1];
    for (int j = beg + h; j < end; j += 2) {
        int src = srcs[j];
        float4 v = ((const float4*)x)[src * 32 + c];
        acc.x += v.x; acc.y += v.y; acc.z += v.z; acc.w += v.w;
    }
    // combine even/odd halves across the wave
    acc.x += __shfl_xor(acc.x, 32);
    acc.y += __shfl_xor(acc.y, 32);
    acc.z += __shfl_xor(acc.z, 32);
    acc.w += __shfl_xor(acc.w, 32);
    if (h == 0) {
        uint2 p;
        p.x = pack2(acc.x, acc.y);
        p.y = pack2(acc.z, acc.w);
        ((uint2*)aggrb)[node * 32 + c] = p;
    }
}

// ---------------- h1 = aggr @ W1 + b1 (bf16 store), col sum/sumsq stats ----------------
__global__ __launch_bounds__(512) void k_gemm1(const u32* __restrict__ aggrb,
                                               const float* __restrict__ W1,
                                               const float* __restrict__ b1,
                                               u32* __restrict__ h1,        // bf16 pairs
                                               float* __restrict__ gstats)  // [512]: sum, sumsq
{
    __shared__ u16 w1s[IN_DIM * HID];      // 64 KB bf16 weights
    __shared__ u16 rbT[IN_DIM * 36];       // rows transposed, [k][r(0..31)+pad]
    __shared__ float slds[HID * 2];        // block stats reduce

    const int tid = threadIdx.x;
    const int lane = tid & 63;
    const int w = tid >> 6;                // wave 0..7

    for (int i = tid; i < IN_DIM * HID; i += 512)
        w1s[i] = f2bf(W1[i]);

    const float4 b1v = ((const float4*)b1)[lane];   // cols 4*lane .. 4*lane+3

    float csum[4] = {0.f,0.f,0.f,0.f}, csq[4] = {0.f,0.f,0.f,0.f};

    const int ngrp = N_NODES / 32;   // 3125 (exact)
    for (int g = blockIdx.x; g < ngrp; g += gridDim.x) {
        const int base = g * 32;
        __syncthreads();   // prev iter readers done; w1s loads done (1st iter)
        // stage 32 rows of aggr (bf16), transposed
        {
            int r = tid >> 4;             // 0..31
            int cq = tid & 15;            // uint4 within row (16 per row)
            uint4 v = ((const uint4*)aggrb)[(base + r) * 16 + cq];
            int c = 8 * cq;
            rbT[(c + 0) * 36 + r] = (u16)(v.x);
            rbT[(c + 1) * 36 + r] = (u16)(v.x >> 16);
            rbT[(c + 2) * 36 + r] = (u16)(v.y);
            rbT[(c + 3) * 36 + r] = (u16)(v.y >> 16);
            rbT[(c + 4) * 36 + r] = (u16)(v.z);
            rbT[(c + 5) * 36 + r] = (u16)(v.z >> 16);
            rbT[(c + 6) * 36 + r] = (u16)(v.w);
            rbT[(c + 7) * 36 + r] = (u16)(v.w >> 16);
        }
        __syncthreads();

        float acc[4][4];
        #pragma unroll
        for (int i = 0; i < 4; ++i)
            #pragma unroll
            for (int j = 0; j < 4; ++j) acc[i][j] = 0.f;

        const u32* w1r = (const u32*)w1s;   // 128 u32 per k-row
        const u32* rbr = (const u32*)rbT;   // 18 u32 per k-row
        #pragma unroll 4
        for (int k = 0; k < IN_DIM; ++k) {
            u32 wa = w1r[k * 128 + 2 * lane];
            u32 wb = w1r[k * 128 + 2 * lane + 1];
            u32 ra = rbr[k * 18 + 2 * w];
            u32 rb = rbr[k * 18 + 2 * w + 1];
            float wc0 = bf2f((u16)wa), wc1 = bf2f((u16)(wa >> 16));
            float wc2 = bf2f((u16)wb), wc3 = bf2f((u16)(wb >> 16));
            float r0 = bf2f((u16)ra), r1 = bf2f((u16)(ra >> 16));
            float r2 = bf2f((u16)rb), r3 = bf2f((u16)(rb >> 16));
            acc[0][0] = fmaf(r0, wc0, acc[0][0]); acc[0][1] = fmaf(r0, wc1, acc[0][1]);
            acc[0][2] = fmaf(r0, wc2, acc[0][2]); acc[0][3] = fmaf(r0, wc3, acc[0][3]);
            acc[1][0] = fmaf(r1, wc0, acc[1][0]); acc[1][1] = fmaf(r1, wc1, acc[1][1]);
            acc[1][2] = fmaf(r1, wc2, acc[1][2]); acc[1][3] = fmaf(r1, wc3, acc[1][3]);
            acc[2][0] = fmaf(r2, wc0, acc[2][0]); acc[2][1] = fmaf(r2, wc1, acc[2][1]);
            acc[2][2] = fmaf(r2, wc2, acc[2][2]); acc[2][3] = fmaf(r2, wc3, acc[2][3]);
            acc[3][0] = fmaf(r3, wc0, acc[3][0]); acc[3][1] = fmaf(r3, wc1, acc[3][1]);
            acc[3][2] = fmaf(r3, wc2, acc[3][2]); acc[3][3] = fmaf(r3, wc3, acc[3][3]);
        }

        #pragma unroll
        for (int i = 0; i < 4; ++i) {
            int row = base + 4 * w + i;
            float h0 = acc[i][0] + b1v.x;
            float h1f = acc[i][1] + b1v.y;
            float h2f = acc[i][2] + b1v.z;
            float h3f = acc[i][3] + b1v.w;
            csum[0] += h0;  csum[1] += h1f;  csum[2] += h2f;  csum[3] += h3f;
            csq[0] += h0 * h0; csq[1] += h1f * h1f; csq[2] += h2f * h2f; csq[3] += h3f * h3f;
            h1[row * 128 + 2 * lane]     = pack2(h0, h1f);
            h1[row * 128 + 2 * lane + 1] = pack2(h2f, h3f);
        }
    }

    __syncthreads();
    slds[tid] = 0.f;                       // tid 0..511 covers 512 slots
    __syncthreads();
    #pragma unroll
    for (int j = 0; j < 4; ++j) {
        atomicAdd(&slds[4 * lane + j], csum[j]);
        atomicAdd(&slds[HID + 4 * lane + j], csq[j]);
    }
    __syncthreads();
    atomicAdd(&gstats[tid], slds[tid]);
}

// ---------------- h2 = relu(bn1(h1)) @ W2 + b2 (f32 -> d_out), stats2 ----------------
__global__ __launch_bounds__(512) void k_gemm2(const u32* __restrict__ h1,
                                               const float* __restrict__ W2,
                                               const float* __restrict__ b2,
                                               const float* __restrict__ g1,
                                               const float* __restrict__ beta1,
                                               const float* __restrict__ gstats,   // [512]
                                               float* __restrict__ out,            // pre-BN h2
                                               float* __restrict__ gstats2)        // [256]
{
    __shared__ u16 w2s[HID * OUT_DIM];     // 64 KB
    __shared__ u16 rbT[HID * 36];          // 18.4 KB
    __shared__ float a1s[HID], b1s[HID];
    __shared__ float slds[OUT_DIM * 2];

    const int tid = threadIdx.x;
    const int lane = tid & 63;
    const int w = tid >> 6;

    for (int i = tid; i < HID * OUT_DIM; i += 512)
        w2s[i] = f2bf(W2[i]);
    if (tid < HID) {
        float s = gstats[tid], sq = gstats[HID + tid];
        float mu = s * (1.0f / N_NODES);
        float var = sq * (1.0f / N_NODES) - mu * mu;
        float inv = rsqrtf(var + BN_EPS);
        float a = g1[tid] * inv;
        a1s[tid] = a;
        b1s[tid] = beta1[tid] - mu * a;
    }

    const float2 b2v = ((const float2*)b2)[lane];   // cols 2*lane, 2*lane+1
    float csum[2] = {0.f,0.f}, csq[2] = {0.f,0.f};

    const int ngrp = N_NODES / 32;
    for (int g = blockIdx.x; g < ngrp; g += gridDim.x) {
        const int base = g * 32;
        __syncthreads();
        // stage 32 rows of h1 with BN1+ReLU applied, transposed bf16
        #pragma unroll
        for (int j = 0; j < 4; ++j) {
            int idx = tid + j * 512;       // 0..2047
            int r = idx >> 6;              // 0..31 (64 uint2 per row)
            int cq = idx & 63;
            uint2 v = ((const uint2*)h1)[(base + r) * 64 + cq];
            int c = 4 * cq;
            float f0 = fmaxf(bf2f((u16)v.x)         * a1s[c + 0] + b1s[c + 0], 0.f);
            float f1 = fmaxf(bf2f((u16)(v.x >> 16)) * a1s[c + 1] + b1s[c + 1], 0.f);
            float f2 = fmaxf(bf2f((u16)v.y)         * a1s[c + 2] + b1s[c + 2], 0.f);
            float f3 = fmaxf(bf2f((u16)(v.y >> 16)) * a1s[c + 3] + b1s[c + 3], 0.f);
            rbT[(c + 0) * 36 + r] = f2bf(f0);
            rbT[(c + 1) * 36 + r] = f2bf(f1);
            rbT[(c + 2) * 36 + r] = f2bf(f2);
            rbT[(c + 3) * 36 + r] = f2bf(f3);
        }
        __syncthreads();

        float acc[4][2] = {{0.f,0.f},{0.f,0.f},{0.f,0.f},{0.f,0.f}};
        const u32* w2r = (const u32*)w2s;   // 64 u32 per k-row
        const u32* rbr = (const u32*)rbT;   // 18 u32 per k-row
        #pragma unroll 4
        for (int k = 0; k < HID; ++k) {
            u32 wv = w2r[k * 64 + lane];
            u32 ra = rbr[k * 18 + 2 * w];
            u32 rb = rbr[k * 18 + 2 * w + 1];
            float wc0 = bf2f((u16)wv), wc1 = bf2f((u16)(wv >> 16));
            float r0 = bf2f((u16)ra), r1 = bf2f((u16)(ra >> 16));
            float r2 = bf2f((u16)rb), r3 = bf2f((u16)(rb >> 16));
            acc[0][0] = fmaf(r0, wc0, acc[0][0]); acc[0][1] = fmaf(r0, wc1, acc[0][1]);
            acc[1][0] = fmaf(r1, wc0, acc[1][0]); acc[1][1] = fmaf(r1, wc1, acc[1][1]);
            acc[2][0] = fmaf(r2, wc0, acc[2][0]); acc[2][1] = fmaf(r2, wc1, acc[2][1]);
            acc[3][0] = fmaf(r3, wc0, acc[3][0]); acc[3][1] = fmaf(r3, wc1, acc[3][1]);
        }

        #pragma unroll
        for (int i = 0; i < 4; ++i) {
            int row = base + 4 * w + i;
            float h0 = acc[i][0] + b2v.x;
            float h1f = acc[i][1] + b2v.y;
            csum[0] += h0;  csum[1] += h1f;
            csq[0] += h0 * h0; csq[1] += h1f * h1f;
            ((float2*)out)[row * 64 + lane] = make_float2(h0, h1f);
        }
    }

    __syncthreads();
    if (tid < OUT_DIM * 2) slds[tid] = 0.f;
    __syncthreads();
    atomicAdd(&slds[2 * lane + 0], csum[0]);
    atomicAdd(&slds[2 * lane + 1], csum[1]);
    atomicAdd(&slds[OUT_DIM + 2 * lane + 0], csq[0]);
    atomicAdd(&slds[OUT_DIM + 2 * lane + 1], csq[1]);
    __syncthreads();
    if (tid < OUT_DIM * 2) atomicAdd(&gstats2[tid], slds[tid]);
}

// ---------------- out = relu(bn2(h2)) in-place ----------------
__global__ __launch_bounds__(256) void k_bn2(float* __restrict__ out,
                                             const float* __restrict__ gstats2,
                                             const float* __restrict__ g2,
                                             const float* __restrict__ beta2) {
    int i = blockIdx.x * 256 + threadIdx.x;      // float4 index
    const int total = N_NODES * OUT_DIM / 4;
    if (i >= total) return;
    float4 v = ((float4*)out)[i];
    int c = (i & 31) * 4;
    float vv[4] = {v.x, v.y, v.z, v.w};
    float res[4];
    #pragma unroll
    for (int j = 0; j < 4; ++j) {
        float s = gstats2[c + j], sq = gstats2[OUT_DIM + c + j];
        float mu = s * (1.0f / N_NODES);
        float var = sq * (1.0f / N_NODES) - mu * mu;
        float inv = rsqrtf(var + BN_EPS);
        float a = g2[c + j] * inv;
        float b = beta2[c + j] - mu * a;
        res[j] = fmaxf(vv[j] * a + b, 0.f);
    }
    ((float4*)out)[i] = make_float4(res[0], res[1], res[2], res[3]);
}

extern "C" void kernel_launch(void* const* d_in, const int* in_sizes, int n_in,
                              void* d_out, int out_size, void* d_ws, size_t ws_size,
                              hipStream_t stream) {
    const float* x     = (const float*)d_in[0];
    const int*   ei    = (const int*)d_in[1];
    const float* epsp  = (const float*)d_in[2];
    const float* W1    = (const float*)d_in[3];
    const float* b1    = (const float*)d_in[4];
    const float* g1    = (const float*)d_in[5];
    const float* beta1 = (const float*)d_in[6];
    const float* W2    = (const float*)d_in[7];
    const float* b2    = (const float*)d_in[8];
    const float* g2    = (const float*)d_in[9];
    const float* beta2 = (const float*)d_in[10];

    char* ws = (char*)d_ws;
    u32*   aggrb   = (u32*)ws;                      // 25.6 MB  bf16 [N][128]
    u32*   h1      = (u32*)(ws + 25600000);         // 51.2 MB  bf16 [N][256]
    int*   srcs    = (int*)(ws + 76800000);         // 6.4 MB
    int*   counts  = (int*)(ws + 83200000);         // 400 KB
    int*   offsets = (int*)(ws + 83600000);         // 400,004 B
    int*   cursor  = (int*)(ws + 84000016);         // 400 KB
    int*   bsum    = (int*)(ws + 84400016);         // 512 B
    float* gstats  = (float*)(ws + 84400528);       // 512 f32 (sum1, sumsq1)
    float* gstats2 = gstats + 512;                  // 256 f32 (sum2, sumsq2)
    float* out = (float*)d_out;

    const int NBLK = (N_NODES + 1023) / 1024;       // 98

    hipMemsetAsync(counts, 0, 400000, stream);
    hipMemsetAsync(gstats, 0, 768 * sizeof(float), stream);

    k_hist<<<(N_EDGES + 255) / 256, 256, 0, stream>>>(ei, counts);
    k_bsum<<<NBLK, 1024, 0, stream>>>(counts, bsum);
    k_bscan<<<1, 128, 0, stream>>>(bsum, NBLK);
    k_offsets<<<NBLK, 1024, 0, stream>>>(counts, bsum, offsets, cursor);
    k_fill<<<(N_EDGES + 255) / 256, 256, 0, stream>>>(ei, cursor, srcs);
    k_aggregate<<<N_NODES / 4, 256, 0, stream>>>(x, srcs, offsets, epsp, aggrb);
    k_gemm1<<<1024, 512, 0, stream>>>(aggrb, W1, b1, h1, gstats);
    k_gemm2<<<1024, 512, 0, stream>>>(h1, W2, b2, g1, beta1, gstats, out, gstats2);
    k_bn2<<<(N_NODES * OUT_DIM / 4 + 255) / 256, 256, 0, stream>>>(out, gstats2, g2, beta2);
}

// Round 3
// 421.072 us; speedup vs baseline: 7.3689x; 1.6699x over previous
//
#include <hip/hip_runtime.h>
#include <hip/hip_bf16.h>

#define N_NODES 100000
#define N_EDGES 1600000
#define IN_DIM  128
#define HID     256
#define OUT_DIM 128
#define BN_EPS  1e-5f

typedef unsigned int u32;
typedef unsigned short u16;
typedef __attribute__((ext_vector_type(8))) short short8v;
typedef __attribute__((ext_vector_type(4))) float f32x4;

__device__ __forceinline__ float bf2f(u16 h) {
    return __uint_as_float(((u32)h) << 16);
}
__device__ __forceinline__ u16 f2bf(float f) {
    u32 u = __float_as_uint(f);
    u32 r = (u + 0x7fffu + ((u >> 16) & 1u)) >> 16;   // round-to-nearest-even
    return (u16)r;
}
__device__ __forceinline__ u32 pack2(float a, float b) {
    return (u32)f2bf(a) | ((u32)f2bf(b) << 16);
}
__device__ __forceinline__ void gload16(const void* g, void* l) {
    __builtin_amdgcn_global_load_lds((const __attribute__((address_space(1))) u32*)g,
                                     (__attribute__((address_space(3))) u32*)l, 16, 0, 0);
}
#define MFMA(a,b,c) __builtin_amdgcn_mfma_f32_16x16x32_bf16(a, b, c, 0, 0, 0)

// ---------------- CSR build: degree histogram ----------------
__global__ __launch_bounds__(256) void k_hist(const int* __restrict__ ei,
                                              int* __restrict__ counts) {
    int e = blockIdx.x * 256 + threadIdx.x;
    if (e < N_EDGES) atomicAdd(&counts[ei[N_EDGES + e]], 1);
}

// ---------------- scan phase A ----------------
__global__ __launch_bounds__(1024) void k_bsum(const int* __restrict__ counts,
                                               int* __restrict__ bsum) {
    __shared__ int s[1024];
    int i = blockIdx.x * 1024 + threadIdx.x;
    s[threadIdx.x] = (i < N_NODES) ? counts[i] : 0;
    __syncthreads();
    for (int d = 512; d > 0; d >>= 1) {
        if (threadIdx.x < d) s[threadIdx.x] += s[threadIdx.x + d];
        __syncthreads();
    }
    if (threadIdx.x == 0) bsum[blockIdx.x] = s[0];
}

// ---------------- scan phase B ----------------
__global__ __launch_bounds__(128) void k_bscan(int* __restrict__ bsum, int nblk) {
    __shared__ int s[128];
    int v = (threadIdx.x < nblk) ? bsum[threadIdx.x] : 0;
    s[threadIdx.x] = v;
    __syncthreads();
    for (int d = 1; d < 128; d <<= 1) {
        int t = (threadIdx.x >= d) ? s[threadIdx.x - d] : 0;
        __syncthreads();
        s[threadIdx.x] += t;
        __syncthreads();
    }
    if (threadIdx.x < nblk) bsum[threadIdx.x] = s[threadIdx.x] - v;  // exclusive
}

// ---------------- scan phase C ----------------
__global__ __launch_bounds__(1024) void k_offsets(const int* __restrict__ counts,
                                                  const int* __restrict__ bsum,
                                                  int* __restrict__ offsets,
                                                  int* __restrict__ cursor) {
    __shared__ int s[1024];
    int i = blockIdx.x * 1024 + threadIdx.x;
    int v = (i < N_NODES) ? counts[i] : 0;
    s[threadIdx.x] = v;
    __syncthreads();
    for (int d = 1; d < 1024; d <<= 1) {
        int t = (threadIdx.x >= d) ? s[threadIdx.x - d] : 0;
        __syncthreads();
        s[threadIdx.x] += t;
        __syncthreads();
    }
    int carry = bsum[blockIdx.x];
    if (i < N_NODES) {
        int excl = carry + s[threadIdx.x] - v;
        offsets[i] = excl;
        cursor[i] = excl;
        if (i == N_NODES - 1) offsets[N_NODES] = carry + s[threadIdx.x];
    }
}

// ---------------- CSR fill ----------------
__global__ __launch_bounds__(256) void k_fill(const int* __restrict__ ei,
                                              int* __restrict__ cursor,
                                              int* __restrict__ srcs) {
    int e = blockIdx.x * 256 + threadIdx.x;
    if (e >= N_EDGES) return;
    int dst = ei[N_EDGES + e];
    int pos = atomicAdd(&cursor[dst], 1);
    srcs[pos] = ei[e];
}

// ---------------- gather-aggregate -> pre-swizzled bf16 rows ----------------
__global__ __launch_bounds__(256) void k_aggregate(const float* __restrict__ x,
                                                   const int* __restrict__ srcs,
                                                   const int* __restrict__ offsets,
                                                   const float* __restrict__ epsp,
                                                   char* __restrict__ aggrb) {
    int node = blockIdx.x * 4 + (threadIdx.x >> 6);   // one wave per node
    int lane = threadIdx.x & 63;
    int c = lane & 31;        // float4 chunk within row
    int h = lane >> 5;        // half-wave: even/odd edges
    float4 acc = make_float4(0.f, 0.f, 0.f, 0.f);
    if (h == 0) {
        float sc = 1.0f + epsp[0];
        float4 v = ((const float4*)x)[node * 32 + c];
        acc.x = v.x * sc; acc.y = v.y * sc; acc.z = v.z * sc; acc.w = v.w * sc;
    }
    int beg = offsets[node], end = offsets[node + 1];
    for (int j = beg + h; j < end; j += 2) {
        int src = srcs[j];
        float4 v = ((const float4*)x)[src * 32 + c];
        acc.x += v.x; acc.y += v.y; acc.z += v.z; acc.w += v.w;
    }
    acc.x += __shfl_xor(acc.x, 32);
    acc.y += __shfl_xor(acc.y, 32);
    acc.z += __shfl_xor(acc.z, 32);
    acc.w += __shfl_xor(acc.w, 32);
    if (h == 0) {
        uint2 p;
        p.x = pack2(acc.x, acc.y);
        p.y = pack2(acc.z, acc.w);
        u32 b = (u32)node * 256 + (u32)c * 8;
        b ^= ((u32)(node & 7)) << 4;        // pre-swizzle for gemm1 LDS reads
        *(uint2*)(aggrb + b) = p;
    }
}

// ---------------- prep: W1->W1T, W2->W2T (bf16, transposed, pre-swizzled) ----------------
__global__ __launch_bounds__(256) void k_prepw(const float* __restrict__ W1,
                                               const float* __restrict__ W2,
                                               char* __restrict__ w1t,
                                               char* __restrict__ w2t) {
    int t = blockIdx.x * 256 + threadIdx.x;   // 0..8191
    u16 tmp[8];
    if (t < 4096) {
        int j = t >> 4, kc = t & 15;          // W1T: [256 j][128 k]
        #pragma unroll
        for (int i = 0; i < 8; ++i) tmp[i] = f2bf(W1[(kc * 8 + i) * HID + j]);
        u32 off = ((u32)(j * 256 + kc * 16)) ^ (((u32)(j & 7)) << 4);
        uint4 q;
        q.x = (u32)tmp[0] | ((u32)tmp[1] << 16);
        q.y = (u32)tmp[2] | ((u32)tmp[3] << 16);
        q.z = (u32)tmp[4] | ((u32)tmp[5] << 16);
        q.w = (u32)tmp[6] | ((u32)tmp[7] << 16);
        *(uint4*)(w1t + off) = q;
    } else {
        int t2 = t - 4096;
        int j = t2 >> 5, kc = t2 & 31;        // W2T: [128 j][256 k]
        #pragma unroll
        for (int i = 0; i < 8; ++i) tmp[i] = f2bf(W2[(kc * 8 + i) * OUT_DIM + j]);
        u32 off = ((u32)(j * 512 + kc * 16)) ^ (((u32)(j & 7)) << 4);
        uint4 q;
        q.x = (u32)tmp[0] | ((u32)tmp[1] << 16);
        q.y = (u32)tmp[2] | ((u32)tmp[3] << 16);
        q.z = (u32)tmp[4] | ((u32)tmp[5] << 16);
        q.w = (u32)tmp[6] | ((u32)tmp[7] << 16);
        *(uint4*)(w2t + off) = q;
    }
}

// ---------------- MFMA gemm1: h1 = aggr @ W1 + b1 (bf16), stats ----------------
__global__ __launch_bounds__(512) void k_gemm1(const char* __restrict__ aggrb,
                                               const char* __restrict__ w1t,
                                               const float* __restrict__ b1,
                                               u16* __restrict__ h1u,
                                               float* __restrict__ gstats) {
    __shared__ u16 Als[160 * 128];    // 40 KB swizzled
    __shared__ u16 Bls[256 * 128];    // 64 KB swizzled
    __shared__ float slds[512];

    const int tid = threadIdx.x, lane = tid & 63, w = tid >> 6;
    const int wr = w >> 2, wc = w & 3;
    const int base = blockIdx.x * 160;

    slds[tid] = 0.f;

    char* lA = (char*)Als;
    char* lB = (char*)Bls;
    const char* ga = aggrb + (size_t)base * 256;
    #pragma unroll
    for (int i = 0; i < 5; ++i)
        gload16(ga + i * 8192 + w * 1024 + (lane << 4), lA + i * 8192 + w * 1024);
    #pragma unroll
    for (int i = 0; i < 8; ++i)
        gload16(w1t + i * 8192 + w * 1024 + (lane << 4), lB + i * 8192 + w * 1024);

    const int rA = lane & 15;
    const int kb = (lane >> 4) << 3;
    const u32 xsw = ((u32)(rA & 7)) << 4;
    int colv[4]; float bcol[4];
    #pragma unroll
    for (int n = 0; n < 4; ++n) { colv[n] = wc * 64 + n * 16 + rA; bcol[n] = b1[colv[n]]; }

    asm volatile("s_waitcnt vmcnt(0)" ::: "memory");
    __syncthreads();

    f32x4 acc[5][4];
    #pragma unroll
    for (int m = 0; m < 5; ++m)
        #pragma unroll
        for (int n = 0; n < 4; ++n) acc[m][n] = (f32x4){0.f, 0.f, 0.f, 0.f};

    #pragma unroll
    for (int ks = 0; ks < 4; ++ks) {
        const int kk2 = (ks * 32 + kb) * 2;
        short8v a[5], b[4];
        #pragma unroll
        for (int m = 0; m < 5; ++m) {
            u32 off = ((u32)((wr * 80 + m * 16 + rA) * 256 + kk2)) ^ xsw;
            a[m] = *(const short8v*)(lA + off);
        }
        #pragma unroll
        for (int n = 0; n < 4; ++n) {
            u32 off = ((u32)(colv[n] * 256 + kk2)) ^ xsw;
            b[n] = *(const short8v*)(lB + off);
        }
        #pragma unroll
        for (int m = 0; m < 5; ++m)
            #pragma unroll
            for (int n = 0; n < 4; ++n)
                acc[m][n] = MFMA(a[m], b[n], acc[m][n]);
    }

    float csum[4] = {0.f,0.f,0.f,0.f}, csq[4] = {0.f,0.f,0.f,0.f};
    #pragma unroll
    for (int m = 0; m < 5; ++m) {
        int r0 = base + wr * 80 + m * 16 + ((lane >> 4) << 2);
        #pragma unroll
        for (int n = 0; n < 4; ++n) {
            f32x4 d = acc[m][n];
            #pragma unroll
            for (int r = 0; r < 4; ++r) {
                float v = d[r] + bcol[n];
                csum[n] += v; csq[n] += v * v;
                h1u[(size_t)(r0 + r) * 256 + colv[n]] = f2bf(v);
            }
        }
    }
    #pragma unroll
    for (int n = 0; n < 4; ++n) {
        csum[n] += __shfl_xor(csum[n], 16); csum[n] += __shfl_xor(csum[n], 32);
        csq[n]  += __shfl_xor(csq[n], 16);  csq[n]  += __shfl_xor(csq[n], 32);
    }
    if (lane < 16) {
        #pragma unroll
        for (int n = 0; n < 4; ++n) {
            atomicAdd(&slds[colv[n]], csum[n]);
            atomicAdd(&slds[256 + colv[n]], csq[n]);
        }
    }
    __syncthreads();
    atomicAdd(&gstats[tid], slds[tid]);
}

// ---------------- MFMA gemm2: out = relu(bn1(h1)) @ W2 + b2 (f32), stats2 ----------------
__global__ __launch_bounds__(512) void k_gemm2(const u16* __restrict__ h1u,
                                               const char* __restrict__ w2t,
                                               const float* __restrict__ b2,
                                               const float* __restrict__ g1,
                                               const float* __restrict__ beta1,
                                               const float* __restrict__ gstats,
                                               float* __restrict__ out,
                                               float* __restrict__ gstats2) {
    __shared__ u16 Als[160 * 128];    // 40 KB (K half), swizzled
    __shared__ u16 Bls[128 * 256];    // 64 KB swizzled
    __shared__ float a1s[256], b1s[256];
    __shared__ float slds[256];

    const int tid = threadIdx.x, lane = tid & 63, w = tid >> 6;
    const int wr = w >> 2, wc = w & 3;
    const int base = blockIdx.x * 160;

    if (tid < 256) {
        float s = gstats[tid], sq = gstats[256 + tid];
        float mu = s * (1.0f / N_NODES);
        float var = sq * (1.0f / N_NODES) - mu * mu;
        float inv = rsqrtf(var + BN_EPS);
        float a = g1[tid] * inv;
        a1s[tid] = a;
        b1s[tid] = beta1[tid] - mu * a;
        slds[tid] = 0.f;
    }

    char* lA = (char*)Als;
    char* lB = (char*)Bls;
    #pragma unroll
    for (int i = 0; i < 8; ++i)
        gload16(w2t + i * 8192 + w * 1024 + (lane << 4), lB + i * 8192 + w * 1024);

    const int rA = lane & 15;
    const int kb = (lane >> 4) << 3;
    const u32 xsw = ((u32)(rA & 7)) << 4;
    int colv[2]; float bcol[2];
    #pragma unroll
    for (int n = 0; n < 2; ++n) { colv[n] = wc * 32 + n * 16 + rA; bcol[n] = b2[colv[n]]; }

    __syncthreads();   // a1s/b1s ready

    f32x4 acc[5][2];
    #pragma unroll
    for (int m = 0; m < 5; ++m)
        #pragma unroll
        for (int n = 0; n < 2; ++n) acc[m][n] = (f32x4){0.f, 0.f, 0.f, 0.f};

    for (int kh = 0; kh < 2; ++kh) {
        // stage A half-tile with BN1+ReLU applied, swizzled
        #pragma unroll
        for (int i = 0; i < 10; ++i) {
            int id = tid + i * 512;       // 0..5119
            int r = id >> 5;              // 0..159
            int c = id & 31;              // uint2 chunk (4 bf16)
            uint2 v = *(const uint2*)(h1u + (size_t)(base + r) * 256 + kh * 128 + c * 4);
            int cg = kh * 128 + c * 4;
            float4 av = *(const float4*)&a1s[cg];
            float4 bv = *(const float4*)&b1s[cg];
            float f0 = fmaxf(bf2f((u16)v.x)         * av.x + bv.x, 0.f);
            float f1 = fmaxf(bf2f((u16)(v.x >> 16)) * av.y + bv.y, 0.f);
            float f2 = fmaxf(bf2f((u16)v.y)         * av.z + bv.z, 0.f);
            float f3 = fmaxf(bf2f((u16)(v.y >> 16)) * av.w + bv.w, 0.f);
            uint2 p; p.x = pack2(f0, f1); p.y = pack2(f2, f3);
            u32 off = ((u32)(r * 256 + c * 8)) ^ (((u32)(r & 7)) << 4);
            *(uint2*)(lA + off) = p;
        }
        if (kh == 0) asm volatile("s_waitcnt vmcnt(0)" ::: "memory");  // W tile landed
        __syncthreads();

        #pragma unroll
        for (int ks = 0; ks < 4; ++ks) {
            const int kk2 = (ks * 32 + kb) * 2;
            short8v a[5], b[2];
            #pragma unroll
            for (int m = 0; m < 5; ++m) {
                u32 off = ((u32)((wr * 80 + m * 16 + rA) * 256 + kk2)) ^ xsw;
                a[m] = *(const short8v*)(lA + off);
            }
            #pragma unroll
            for (int n = 0; n < 2; ++n) {
                u32 off = ((u32)(colv[n] * 512 + kh * 256 + kk2)) ^ xsw;
                b[n] = *(const short8v*)(lB + off);
            }
            #pragma unroll
            for (int m = 0; m < 5; ++m)
                #pragma unroll
                for (int n = 0; n < 2; ++n)
                    acc[m][n] = MFMA(a[m], b[n], acc[m][n]);
        }
        __syncthreads();   // Als reads done before restage / epilogue
    }

    float csum[2] = {0.f,0.f}, csq[2] = {0.f,0.f};
    #pragma unroll
    for (int m = 0; m < 5; ++m) {
        int r0 = base + wr * 80 + m * 16 + ((lane >> 4) << 2);
        #pragma unroll
        for (int n = 0; n < 2; ++n) {
            f32x4 d = acc[m][n];
            #pragma unroll
            for (int r = 0; r < 4; ++r) {
                float v = d[r] + bcol[n];
                csum[n] += v; csq[n] += v * v;
                out[(size_t)(r0 + r) * 128 + colv[n]] = v;
            }
        }
    }
    #pragma unroll
    for (int n = 0; n < 2; ++n) {
        csum[n] += __shfl_xor(csum[n], 16); csum[n] += __shfl_xor(csum[n], 32);
        csq[n]  += __shfl_xor(csq[n], 16);  csq[n]  += __shfl_xor(csq[n], 32);
    }
    if (lane < 16) {
        #pragma unroll
        for (int n = 0; n < 2; ++n) {
            atomicAdd(&slds[colv[n]], csum[n]);
            atomicAdd(&slds[128 + colv[n]], csq[n]);
        }
    }
    __syncthreads();
    if (tid < 256) atomicAdd(&gstats2[tid], slds[tid]);
}

// ---------------- out = relu(bn2(h2)) in-place ----------------
__global__ __launch_bounds__(256) void k_bn2(float* __restrict__ out,
                                             const float* __restrict__ gstats2,
                                             const float* __restrict__ g2,
                                             const float* __restrict__ beta2) {
    int i = blockIdx.x * 256 + threadIdx.x;      // float4 index
    const int total = N_NODES * OUT_DIM / 4;
    if (i >= total) return;
    float4 v = ((float4*)out)[i];
    int c = (i & 31) * 4;
    float vv[4] = {v.x, v.y, v.z, v.w};
    float res[4];
    #pragma unroll
    for (int j = 0; j < 4; ++j) {
        float s = gstats2[c + j], sq = gstats2[OUT_DIM + c + j];
        float mu = s * (1.0f / N_NODES);
        float var = sq * (1.0f / N_NODES) - mu * mu;
        float inv = rsqrtf(var + BN_EPS);
        float a = g2[c + j] * inv;
        float b = beta2[c + j] - mu * a;
        res[j] = fmaxf(vv[j] * a + b, 0.f);
    }
    ((float4*)out)[i] = make_float4(res[0], res[1], res[2], res[3]);
}

extern "C" void kernel_launch(void* const* d_in, const int* in_sizes, int n_in,
                              void* d_out, int out_size, void* d_ws, size_t ws_size,
                              hipStream_t stream) {
    const float* x     = (const float*)d_in[0];
    const int*   ei    = (const int*)d_in[1];
    const float* epsp  = (const float*)d_in[2];
    const float* W1    = (const float*)d_in[3];
    const float* b1    = (const float*)d_in[4];
    const float* g1    = (const float*)d_in[5];
    const float* beta1 = (const float*)d_in[6];
    const float* W2    = (const float*)d_in[7];
    const float* b2    = (const float*)d_in[8];
    const float* g2    = (const float*)d_in[9];
    const float* beta2 = (const float*)d_in[10];

    char* ws = (char*)d_ws;
    char*  aggrb   = ws;                            // 25.6 MB  bf16 [N][128] pre-swizzled
    u16*   h1u     = (u16*)(ws + 25600000);         // 51.2 MB  bf16 [N][256]
    int*   srcs    = (int*)(ws + 76800000);         // 6.4 MB
    int*   counts  = (int*)(ws + 83200000);         // 400 KB
    int*   offsets = (int*)(ws + 83600000);         // 400,004 B
    int*   cursor  = (int*)(ws + 84000016);         // 400 KB
    int*   bsum    = (int*)(ws + 84400016);         // 512 B
    float* gstats  = (float*)(ws + 84400528);       // 512 f32
    float* gstats2 = gstats + 512;                  // 256 f32
    char*  w1t     = ws + 84403712;                 // 64 KB bf16 W1^T swizzled
    char*  w2t     = ws + 84469248;                 // 64 KB bf16 W2^T swizzled
    float* out = (float*)d_out;

    const int NBLK = (N_NODES + 1023) / 1024;       // 98

    hipMemsetAsync(counts, 0, 400000, stream);
    hipMemsetAsync(gstats, 0, 768 * sizeof(float), stream);

    k_hist<<<(N_EDGES + 255) / 256, 256, 0, stream>>>(ei, counts);
    k_bsum<<<NBLK, 1024, 0, stream>>>(counts, bsum);
    k_bscan<<<1, 128, 0, stream>>>(bsum, NBLK);
    k_offsets<<<NBLK, 1024, 0, stream>>>(counts, bsum, offsets, cursor);
    k_fill<<<(N_EDGES + 255) / 256, 256, 0, stream>>>(ei, cursor, srcs);
    k_prepw<<<32, 256, 0, stream>>>(W1, W2, w1t, w2t);
    k_aggregate<<<N_NODES / 4, 256, 0, stream>>>(x, srcs, offsets, epsp, aggrb);
    k_gemm1<<<625, 512, 0, stream>>>(aggrb, w1t, b1, h1u, gstats);
    k_gemm2<<<625, 512, 0, stream>>>(h1u, w2t, b2, g1, beta1, gstats, out, gstats2);
    k_bn2<<<(N_NODES * OUT_DIM / 4 + 255) / 256, 256, 0, stream>>>(out, gstats2, g2, beta2);
}

// Round 4
// 282.335 us; speedup vs baseline: 10.9900x; 1.4914x over previous
//
#include <hip/hip_runtime.h>
#include <hip/hip_bf16.h>

#define N_NODES 100000
#define N_EDGES 1600000
#define IN_DIM  128
#define HID     256
#define OUT_DIM 128
#define BN_EPS  1e-5f

typedef unsigned int u32;
typedef unsigned short u16;
typedef __attribute__((ext_vector_type(8))) short short8v;
typedef __attribute__((ext_vector_type(4))) float f32x4;

__device__ __forceinline__ float bf2f(u16 h) {
    return __uint_as_float(((u32)h) << 16);
}
__device__ __forceinline__ u16 f2bf(float f) {
    u32 u = __float_as_uint(f);
    u32 r = (u + 0x7fffu + ((u >> 16) & 1u)) >> 16;   // round-to-nearest-even
    return (u16)r;
}
__device__ __forceinline__ u32 pack2(float a, float b) {
    return (u32)f2bf(a) | ((u32)f2bf(b) << 16);
}
__device__ __forceinline__ void gload16(const void* g, void* l) {
    __builtin_amdgcn_global_load_lds((const __attribute__((address_space(1))) u32*)g,
                                     (__attribute__((address_space(3))) u32*)l, 16, 0, 0);
}
#define MFMA(a,b,c) __builtin_amdgcn_mfma_f32_16x16x32_bf16(a, b, c, 0, 0, 0)

// ---------------- x -> bf16 (packed pairs) ----------------
__global__ __launch_bounds__(256) void k_prepx(const float* __restrict__ x,
                                               uint2* __restrict__ xb) {
    int i = blockIdx.x * 256 + threadIdx.x;     // float4 index
    const int total = N_NODES * 32;
    if (i < total) {
        float4 v = ((const float4*)x)[i];
        uint2 p;
        p.x = pack2(v.x, v.y);
        p.y = pack2(v.z, v.w);
        xb[i] = p;
    }
}

// ---------------- linked-list build: head[dst] -> chain of (next, src) ----------------
__global__ __launch_bounds__(256) void k_link(const int* __restrict__ ei,
                                              int* __restrict__ head,
                                              int2* __restrict__ nxt) {
    int e = blockIdx.x * 256 + threadIdx.x;
    if (e >= N_EDGES) return;
    int dst = ei[N_EDGES + e];
    int src = ei[e];
    int old = atomicExch(&head[dst], e);
    nxt[e] = make_int2(old, src);
}

// ---------------- gather-aggregate via chain walk -> pre-swizzled bf16 rows ----------------
__global__ __launch_bounds__(256) void k_aggregate(const uint2* __restrict__ xb,
                                                   const int2* __restrict__ nxt,
                                                   const int* __restrict__ head,
                                                   const float* __restrict__ epsp,
                                                   char* __restrict__ aggrb) {
    int node = blockIdx.x * 8 + (threadIdx.x >> 5);   // one half-wave per node
    int l = threadIdx.x & 31;                          // 32 lanes x 8B = 256B row
    uint2 s = xb[node * 32 + l];
    float sc = 1.0f + epsp[0];
    float a0 = bf2f((u16)s.x) * sc, a1 = bf2f((u16)(s.x >> 16)) * sc;
    float a2 = bf2f((u16)s.y) * sc, a3 = bf2f((u16)(s.y >> 16)) * sc;
    int e = head[node];
    while (e >= 0) {
        int2 nv = nxt[e];          // wave-uniform address -> broadcast fetch
        int src = nv.y;
        e = nv.x;
        uint2 v = xb[src * 32 + l];
        a0 += bf2f((u16)v.x); a1 += bf2f((u16)(v.x >> 16));
        a2 += bf2f((u16)v.y); a3 += bf2f((u16)(v.y >> 16));
    }
    u32 b = ((u32)node * 256 + (u32)l * 8) ^ (((u32)(node & 7)) << 4);  // pre-swizzle
    uint2 p; p.x = pack2(a0, a1); p.y = pack2(a2, a3);
    *(uint2*)(aggrb + b) = p;
}

// ---------------- prep: W1->W1T, W2->W2T (bf16, transposed, pre-swizzled) ----------------
__global__ __launch_bounds__(256) void k_prepw(const float* __restrict__ W1,
                                               const float* __restrict__ W2,
                                               char* __restrict__ w1t,
                                               char* __restrict__ w2t) {
    int t = blockIdx.x * 256 + threadIdx.x;   // 0..8191
    u16 tmp[8];
    if (t < 4096) {
        int j = t >> 4, kc = t & 15;          // W1T: [256 j][128 k]
        #pragma unroll
        for (int i = 0; i < 8; ++i) tmp[i] = f2bf(W1[(kc * 8 + i) * HID + j]);
        u32 off = ((u32)(j * 256 + kc * 16)) ^ (((u32)(j & 7)) << 4);
        uint4 q;
        q.x = (u32)tmp[0] | ((u32)tmp[1] << 16);
        q.y = (u32)tmp[2] | ((u32)tmp[3] << 16);
        q.z = (u32)tmp[4] | ((u32)tmp[5] << 16);
        q.w = (u32)tmp[6] | ((u32)tmp[7] << 16);
        *(uint4*)(w1t + off) = q;
    } else {
        int t2 = t - 4096;
        int j = t2 >> 5, kc = t2 & 31;        // W2T: [128 j][256 k]
        #pragma unroll
        for (int i = 0; i < 8; ++i) tmp[i] = f2bf(W2[(kc * 8 + i) * OUT_DIM + j]);
        u32 off = ((u32)(j * 512 + kc * 16)) ^ (((u32)(j & 7)) << 4);
        uint4 q;
        q.x = (u32)tmp[0] | ((u32)tmp[1] << 16);
        q.y = (u32)tmp[2] | ((u32)tmp[3] << 16);
        q.z = (u32)tmp[4] | ((u32)tmp[5] << 16);
        q.w = (u32)tmp[6] | ((u32)tmp[7] << 16);
        *(uint4*)(w2t + off) = q;
    }
}

// ---------------- MFMA gemm1: h1 = aggr @ W1 + b1 (bf16), stats ----------------
__global__ __launch_bounds__(512) void k_gemm1(const char* __restrict__ aggrb,
                                               const char* __restrict__ w1t,
                                               const float* __restrict__ b1,
                                               u16* __restrict__ h1u,
                                               float* __restrict__ gstats) {
    __shared__ u16 Als[160 * 128];    // 40 KB swizzled
    __shared__ u16 Bls[256 * 128];    // 64 KB swizzled
    __shared__ float slds[512];

    const int tid = threadIdx.x, lane = tid & 63, w = tid >> 6;
    const int wr = w >> 2, wc = w & 3;
    const int base = blockIdx.x * 160;

    slds[tid] = 0.f;

    char* lA = (char*)Als;
    char* lB = (char*)Bls;
    const char* ga = aggrb + (size_t)base * 256;
    #pragma unroll
    for (int i = 0; i < 5; ++i)
        gload16(ga + i * 8192 + w * 1024 + (lane << 4), lA + i * 8192 + w * 1024);
    #pragma unroll
    for (int i = 0; i < 8; ++i)
        gload16(w1t + i * 8192 + w * 1024 + (lane << 4), lB + i * 8192 + w * 1024);

    const int rA = lane & 15;
    const int kb = (lane >> 4) << 3;
    const u32 xsw = ((u32)(rA & 7)) << 4;
    int colv[4]; float bcol[4];
    #pragma unroll
    for (int n = 0; n < 4; ++n) { colv[n] = wc * 64 + n * 16 + rA; bcol[n] = b1[colv[n]]; }

    asm volatile("s_waitcnt vmcnt(0)" ::: "memory");
    __syncthreads();

    f32x4 acc[5][4];
    #pragma unroll
    for (int m = 0; m < 5; ++m)
        #pragma unroll
        for (int n = 0; n < 4; ++n) acc[m][n] = (f32x4){0.f, 0.f, 0.f, 0.f};

    #pragma unroll
    for (int ks = 0; ks < 4; ++ks) {
        const int kk2 = (ks * 32 + kb) * 2;
        short8v a[5], b[4];
        #pragma unroll
        for (int m = 0; m < 5; ++m) {
            u32 off = ((u32)((wr * 80 + m * 16 + rA) * 256 + kk2)) ^ xsw;
            a[m] = *(const short8v*)(lA + off);
        }
        #pragma unroll
        for (int n = 0; n < 4; ++n) {
            u32 off = ((u32)(colv[n] * 256 + kk2)) ^ xsw;
            b[n] = *(const short8v*)(lB + off);
        }
        #pragma unroll
        for (int m = 0; m < 5; ++m)
            #pragma unroll
            for (int n = 0; n < 4; ++n)
                acc[m][n] = MFMA(a[m], b[n], acc[m][n]);
    }

    float csum[4] = {0.f,0.f,0.f,0.f}, csq[4] = {0.f,0.f,0.f,0.f};
    #pragma unroll
    for (int m = 0; m < 5; ++m) {
        int r0 = base + wr * 80 + m * 16 + ((lane >> 4) << 2);
        #pragma unroll
        for (int n = 0; n < 4; ++n) {
            f32x4 d = acc[m][n];
            #pragma unroll
            for (int r = 0; r < 4; ++r) {
                float v = d[r] + bcol[n];
                csum[n] += v; csq[n] += v * v;
                h1u[(size_t)(r0 + r) * 256 + colv[n]] = f2bf(v);
            }
        }
    }
    #pragma unroll
    for (int n = 0; n < 4; ++n) {
        csum[n] += __shfl_xor(csum[n], 16); csum[n] += __shfl_xor(csum[n], 32);
        csq[n]  += __shfl_xor(csq[n], 16);  csq[n]  += __shfl_xor(csq[n], 32);
    }
    if (lane < 16) {
        #pragma unroll
        for (int n = 0; n < 4; ++n) {
            atomicAdd(&slds[colv[n]], csum[n]);
            atomicAdd(&slds[256 + colv[n]], csq[n]);
        }
    }
    __syncthreads();
    atomicAdd(&gstats[tid], slds[tid]);
}

// ---------------- MFMA gemm2: out = relu(bn1(h1)) @ W2 + b2 (f32), stats2 ----------------
__global__ __launch_bounds__(512) void k_gemm2(const u16* __restrict__ h1u,
                                               const char* __restrict__ w2t,
                                               const float* __restrict__ b2,
                                               const float* __restrict__ g1,
                                               const float* __restrict__ beta1,
                                               const float* __restrict__ gstats,
                                               float* __restrict__ out,
                                               float* __restrict__ gstats2) {
    __shared__ u16 Als[160 * 128];    // 40 KB (K half), swizzled
    __shared__ u16 Bls[128 * 256];    // 64 KB swizzled
    __shared__ float a1s[256], b1s[256];
    __shared__ float slds[256];

    const int tid = threadIdx.x, lane = tid & 63, w = tid >> 6;
    const int wr = w >> 2, wc = w & 3;
    const int base = blockIdx.x * 160;

    if (tid < 256) {
        float s = gstats[tid], sq = gstats[256 + tid];
        float mu = s * (1.0f / N_NODES);
        float var = sq * (1.0f / N_NODES) - mu * mu;
        float inv = rsqrtf(var + BN_EPS);
        float a = g1[tid] * inv;
        a1s[tid] = a;
        b1s[tid] = beta1[tid] - mu * a;
        slds[tid] = 0.f;
    }

    char* lA = (char*)Als;
    char* lB = (char*)Bls;
    #pragma unroll
    for (int i = 0; i < 8; ++i)
        gload16(w2t + i * 8192 + w * 1024 + (lane << 4), lB + i * 8192 + w * 1024);

    const int rA = lane & 15;
    const int kb = (lane >> 4) << 3;
    const u32 xsw = ((u32)(rA & 7)) << 4;
    int colv[2]; float bcol[2];
    #pragma unroll
    for (int n = 0; n < 2; ++n) { colv[n] = wc * 32 + n * 16 + rA; bcol[n] = b2[colv[n]]; }

    __syncthreads();   // a1s/b1s ready

    f32x4 acc[5][2];
    #pragma unroll
    for (int m = 0; m < 5; ++m)
        #pragma unroll
        for (int n = 0; n < 2; ++n) acc[m][n] = (f32x4){0.f, 0.f, 0.f, 0.f};

    for (int kh = 0; kh < 2; ++kh) {
        // stage A half-tile with BN1+ReLU applied, swizzled
        #pragma unroll
        for (int i = 0; i < 10; ++i) {
            int id = tid + i * 512;       // 0..5119
            int r = id >> 5;              // 0..159
            int c = id & 31;              // uint2 chunk (4 bf16)
            uint2 v = *(const uint2*)(h1u + (size_t)(base + r) * 256 + kh * 128 + c * 4);
            int cg = kh * 128 + c * 4;
            float4 av = *(const float4*)&a1s[cg];
            float4 bv = *(const float4*)&b1s[cg];
            float f0 = fmaxf(bf2f((u16)v.x)         * av.x + bv.x, 0.f);
            float f1 = fmaxf(bf2f((u16)(v.x >> 16)) * av.y + bv.y, 0.f);
            float f2 = fmaxf(bf2f((u16)v.y)         * av.z + bv.z, 0.f);
            float f3 = fmaxf(bf2f((u16)(v.y >> 16)) * av.w + bv.w, 0.f);
            uint2 p; p.x = pack2(f0, f1); p.y = pack2(f2, f3);
            u32 off = ((u32)(r * 256 + c * 8)) ^ (((u32)(r & 7)) << 4);
            *(uint2*)(lA + off) = p;
        }
        if (kh == 0) asm volatile("s_waitcnt vmcnt(0)" ::: "memory");  // W tile landed
        __syncthreads();

        #pragma unroll
        for (int ks = 0; ks < 4; ++ks) {
            const int kk2 = (ks * 32 + kb) * 2;
            short8v a[5], b[2];
            #pragma unroll
            for (int m = 0; m < 5; ++m) {
                u32 off = ((u32)((wr * 80 + m * 16 + rA) * 256 + kk2)) ^ xsw;
                a[m] = *(const short8v*)(lA + off);
            }
            #pragma unroll
            for (int n = 0; n < 2; ++n) {
                u32 off = ((u32)(colv[n] * 512 + kh * 256 + kk2)) ^ xsw;
                b[n] = *(const short8v*)(lB + off);
            }
            #pragma unroll
            for (int m = 0; m < 5; ++m)
                #pragma unroll
                for (int n = 0; n < 2; ++n)
                    acc[m][n] = MFMA(a[m], b[n], acc[m][n]);
        }
        __syncthreads();   // Als reads done before restage / epilogue
    }

    float csum[2] = {0.f,0.f}, csq[2] = {0.f,0.f};
    #pragma unroll
    for (int m = 0; m < 5; ++m) {
        int r0 = base + wr * 80 + m * 16 + ((lane >> 4) << 2);
        #pragma unroll
        for (int n = 0; n < 2; ++n) {
            f32x4 d = acc[m][n];
            #pragma unroll
            for (int r = 0; r < 4; ++r) {
                float v = d[r] + bcol[n];
                csum[n] += v; csq[n] += v * v;
                out[(size_t)(r0 + r) * 128 + colv[n]] = v;
            }
        }
    }
    #pragma unroll
    for (int n = 0; n < 2; ++n) {
        csum[n] += __shfl_xor(csum[n], 16); csum[n] += __shfl_xor(csum[n], 32);
        csq[n]  += __shfl_xor(csq[n], 16);  csq[n]  += __shfl_xor(csq[n], 32);
    }
    if (lane < 16) {
        #pragma unroll
        for (int n = 0; n < 2; ++n) {
            atomicAdd(&slds[colv[n]], csum[n]);
            atomicAdd(&slds[128 + colv[n]], csq[n]);
        }
    }
    __syncthreads();
    if (tid < 256) atomicAdd(&gstats2[tid], slds[tid]);
}

// ---------------- out = relu(bn2(h2)) in-place ----------------
__global__ __launch_bounds__(256) void k_bn2(float* __restrict__ out,
                                             const float* __restrict__ gstats2,
                                             const float* __restrict__ g2,
                                             const float* __restrict__ beta2) {
    int i = blockIdx.x * 256 + threadIdx.x;      // float4 index
    const int total = N_NODES * OUT_DIM / 4;
    if (i >= total) return;
    float4 v = ((float4*)out)[i];
    int c = (i & 31) * 4;
    float vv[4] = {v.x, v.y, v.z, v.w};
    float res[4];
    #pragma unroll
    for (int j = 0; j < 4; ++j) {
        float s = gstats2[c + j], sq = gstats2[OUT_DIM + c + j];
        float mu = s * (1.0f / N_NODES);
        float var = sq * (1.0f / N_NODES) - mu * mu;
        float inv = rsqrtf(var + BN_EPS);
        float a = g2[c + j] * inv;
        float b = beta2[c + j] - mu * a;
        res[j] = fmaxf(vv[j] * a + b, 0.f);
    }
    ((float4*)out)[i] = make_float4(res[0], res[1], res[2], res[3]);
}

extern "C" void kernel_launch(void* const* d_in, const int* in_sizes, int n_in,
                              void* d_out, int out_size, void* d_ws, size_t ws_size,
                              hipStream_t stream) {
    const float* x     = (const float*)d_in[0];
    const int*   ei    = (const int*)d_in[1];
    const float* epsp  = (const float*)d_in[2];
    const float* W1    = (const float*)d_in[3];
    const float* b1    = (const float*)d_in[4];
    const float* g1    = (const float*)d_in[5];
    const float* beta1 = (const float*)d_in[6];
    const float* W2    = (const float*)d_in[7];
    const float* b2    = (const float*)d_in[8];
    const float* g2    = (const float*)d_in[9];
    const float* beta2 = (const float*)d_in[10];

    char* ws = (char*)d_ws;
    char*  aggrb   = ws;                            // [0, 25.6M)   bf16 [N][128] pre-swizzled
    u16*   h1u     = (u16*)(ws + 25600000);         // [25.6M, 76.8M) bf16 [N][256] (gemm1 output)
    // nxt/head/xb live INSIDE the h1u region (dead before gemm1 writes it):
    int2*  nxt     = (int2*)(ws + 25600000);        // 12.8 MB (next, src) per edge
    int*   head    = (int*)(ws + 38400000);         // 400 KB
    uint2* xb      = (uint2*)(ws + 40000000);       // 25.6 MB bf16 [N][128]
    float* gstats  = (float*)(ws + 76800000);       // 512 f32
    float* gstats2 = gstats + 512;                  // 256 f32
    char*  w1t     = ws + 76804096;                 // 64 KB bf16 W1^T swizzled
    char*  w2t     = ws + 76869632;                 // 64 KB bf16 W2^T swizzled
    float* out = (float*)d_out;

    hipMemsetAsync(head, 0xFF, 400000, stream);     // head = -1
    hipMemsetAsync(gstats, 0, 768 * sizeof(float), stream);

    k_prepx<<<(N_NODES * 32 + 255) / 256, 256, 0, stream>>>(x, xb);
    k_link<<<(N_EDGES + 255) / 256, 256, 0, stream>>>(ei, head, nxt);
    k_prepw<<<32, 256, 0, stream>>>(W1, W2, w1t, w2t);
    k_aggregate<<<N_NODES / 8, 256, 0, stream>>>(xb, nxt, head, epsp, aggrb);
    k_gemm1<<<625, 512, 0, stream>>>(aggrb, w1t, b1, h1u, gstats);
    k_gemm2<<<625, 512, 0, stream>>>(h1u, w2t, b2, g1, beta1, gstats, out, gstats2);
    k_bn2<<<(N_NODES * OUT_DIM / 4 + 255) / 256, 256, 0, stream>>>(out, gstats2, g2, beta2);
}

// Round 5
// 259.078 us; speedup vs baseline: 11.9765x; 1.0898x over previous
//
#include <hip/hip_runtime.h>
#include <hip/hip_bf16.h>

#define N_NODES 100000
#define N_EDGES 1600000
#define IN_DIM  128
#define HID     256
#define OUT_DIM 128
#define BN_EPS  1e-5f

typedef unsigned int u32;
typedef unsigned short u16;
typedef __attribute__((ext_vector_type(8))) short short8v;
typedef __attribute__((ext_vector_type(4))) float f32x4;

__device__ __forceinline__ float bf2f(u16 h) {
    return __uint_as_float(((u32)h) << 16);
}
__device__ __forceinline__ u16 f2bf(float f) {
    u32 u = __float_as_uint(f);
    u32 r = (u + 0x7fffu + ((u >> 16) & 1u)) >> 16;   // round-to-nearest-even
    return (u16)r;
}
__device__ __forceinline__ u32 pack2(float a, float b) {
    return (u32)f2bf(a) | ((u32)f2bf(b) << 16);
}
__device__ __forceinline__ void gload16(const void* g, void* l) {
    __builtin_amdgcn_global_load_lds((const __attribute__((address_space(1))) u32*)g,
                                     (__attribute__((address_space(3))) u32*)l, 16, 0, 0);
}
#define MFMA(a,b,c) __builtin_amdgcn_mfma_f32_16x16x32_bf16(a, b, c, 0, 0, 0)

// ---------------- fused prep: x->bf16, linked-list build, W transpose ----------------
__global__ __launch_bounds__(256) void k_prep(const float* __restrict__ x,
                                              const int* __restrict__ ei,
                                              const float* __restrict__ W1,
                                              const float* __restrict__ W2,
                                              uint2* __restrict__ xb,
                                              int* __restrict__ head2,
                                              int2* __restrict__ nxt,
                                              char* __restrict__ w1t,
                                              char* __restrict__ w2t) {
    int t = blockIdx.x * 256 + threadIdx.x;     // grid = 12500*256 = 3.2M exact
    {   // x -> bf16 packed (t = float4 index, 3.2M total)
        float4 v = ((const float4*)x)[t];
        uint2 p;
        p.x = pack2(v.x, v.y);
        p.y = pack2(v.z, v.w);
        xb[t] = p;
    }
    if (t < N_EDGES) {   // linked-list: two parity chains per node
        int dst = ei[N_EDGES + t];
        int src = ei[t];
        int old = atomicExch(&head2[dst * 2 + (t & 1)], t);
        nxt[t] = make_int2(old, src);
    }
    if (t < 8192) {      // W1->W1T, W2->W2T (bf16, transposed, pre-swizzled)
        u16 tmp[8];
        if (t < 4096) {
            int j = t >> 4, kc = t & 15;          // W1T: [256 j][128 k]
            #pragma unroll
            for (int i = 0; i < 8; ++i) tmp[i] = f2bf(W1[(kc * 8 + i) * HID + j]);
            u32 off = ((u32)(j * 256 + kc * 16)) ^ (((u32)(j & 7)) << 4);
            uint4 q;
            q.x = (u32)tmp[0] | ((u32)tmp[1] << 16);
            q.y = (u32)tmp[2] | ((u32)tmp[3] << 16);
            q.z = (u32)tmp[4] | ((u32)tmp[5] << 16);
            q.w = (u32)tmp[6] | ((u32)tmp[7] << 16);
            *(uint4*)(w1t + off) = q;
        } else {
            int t2 = t - 4096;
            int j = t2 >> 5, kc = t2 & 31;        // W2T: [128 j][256 k]
            #pragma unroll
            for (int i = 0; i < 8; ++i) tmp[i] = f2bf(W2[(kc * 8 + i) * OUT_DIM + j]);
            u32 off = ((u32)(j * 512 + kc * 16)) ^ (((u32)(j & 7)) << 4);
            uint4 q;
            q.x = (u32)tmp[0] | ((u32)tmp[1] << 16);
            q.y = (u32)tmp[2] | ((u32)tmp[3] << 16);
            q.z = (u32)tmp[4] | ((u32)tmp[5] << 16);
            q.w = (u32)tmp[6] | ((u32)tmp[7] << 16);
            *(uint4*)(w2t + off) = q;
        }
    }
}

// ---------------- gather-aggregate: quarter-wave per (node,parity) chain ----------------
__global__ __launch_bounds__(256) void k_aggregate(const uint4* __restrict__ xb4,
                                                   const int2* __restrict__ nxt,
                                                   const int* __restrict__ head2,
                                                   const float* __restrict__ epsp,
                                                   char* __restrict__ aggrb) {
    const int lane = threadIdx.x & 63;
    const int w = threadIdx.x >> 6;
    const int q = lane >> 4, l = lane & 15;     // quarter, lane-in-quarter
    const int nq = q >> 1, p = q & 1;           // node-in-wave, parity chain
    const int node = blockIdx.x * 8 + w * 2 + nq;

    float a[8];
    #pragma unroll
    for (int i = 0; i < 8; ++i) a[i] = 0.f;

    if (p == 0) {   // self term (1+eps)*x
        float sc = 1.0f + epsp[0];
        uint4 v = xb4[node * 16 + l];
        a[0] = bf2f((u16)v.x) * sc;  a[1] = bf2f((u16)(v.x >> 16)) * sc;
        a[2] = bf2f((u16)v.y) * sc;  a[3] = bf2f((u16)(v.y >> 16)) * sc;
        a[4] = bf2f((u16)v.z) * sc;  a[5] = bf2f((u16)(v.z >> 16)) * sc;
        a[6] = bf2f((u16)v.w) * sc;  a[7] = bf2f((u16)(v.w >> 16)) * sc;
    }
    int e = head2[node * 2 + p];
    while (e >= 0) {
        int2 nv = nxt[e];           // quarter-uniform -> broadcast
        e = nv.x;
        uint4 v = xb4[nv.y * 16 + l];
        a[0] += bf2f((u16)v.x);  a[1] += bf2f((u16)(v.x >> 16));
        a[2] += bf2f((u16)v.y);  a[3] += bf2f((u16)(v.y >> 16));
        a[4] += bf2f((u16)v.z);  a[5] += bf2f((u16)(v.z >> 16));
        a[6] += bf2f((u16)v.w);  a[7] += bf2f((u16)(v.w >> 16));
    }
    #pragma unroll
    for (int i = 0; i < 8; ++i) a[i] += __shfl_xor(a[i], 16);   // merge parities
    if (p == 0) {
        uint4 o;
        o.x = pack2(a[0], a[1]);
        o.y = pack2(a[2], a[3]);
        o.z = pack2(a[4], a[5]);
        o.w = pack2(a[6], a[7]);
        u32 b = ((u32)node * 256 + (u32)l * 16) ^ (((u32)(node & 7)) << 4);  // pre-swizzle
        *(uint4*)(aggrb + b) = o;
    }
}

// ---------------- MFMA gemm1: h1 = aggr @ W1 + b1 (bf16), stats ----------------
__global__ __launch_bounds__(512) void k_gemm1(const char* __restrict__ aggrb,
                                               const char* __restrict__ w1t,
                                               const float* __restrict__ b1,
                                               u16* __restrict__ h1u,
                                               float* __restrict__ gstats) {
    __shared__ u16 Als[160 * 128];    // 40 KB swizzled
    __shared__ u16 Bls[256 * 128];    // 64 KB swizzled
    __shared__ float slds[512];

    const int tid = threadIdx.x, lane = tid & 63, w = tid >> 6;
    const int wr = w >> 2, wc = w & 3;
    const int base = blockIdx.x * 160;

    slds[tid] = 0.f;

    char* lA = (char*)Als;
    char* lB = (char*)Bls;
    const char* ga = aggrb + (size_t)base * 256;
    #pragma unroll
    for (int i = 0; i < 5; ++i)
        gload16(ga + i * 8192 + w * 1024 + (lane << 4), lA + i * 8192 + w * 1024);
    #pragma unroll
    for (int i = 0; i < 8; ++i)
        gload16(w1t + i * 8192 + w * 1024 + (lane << 4), lB + i * 8192 + w * 1024);

    const int rA = lane & 15;
    const int kb = (lane >> 4) << 3;
    const u32 xsw = ((u32)(rA & 7)) << 4;
    int colv[4]; float bcol[4];
    #pragma unroll
    for (int n = 0; n < 4; ++n) { colv[n] = wc * 64 + n * 16 + rA; bcol[n] = b1[colv[n]]; }

    asm volatile("s_waitcnt vmcnt(0)" ::: "memory");
    __syncthreads();

    f32x4 acc[5][4];
    #pragma unroll
    for (int m = 0; m < 5; ++m)
        #pragma unroll
        for (int n = 0; n < 4; ++n) acc[m][n] = (f32x4){0.f, 0.f, 0.f, 0.f};

    #pragma unroll
    for (int ks = 0; ks < 4; ++ks) {
        const int kk2 = (ks * 32 + kb) * 2;
        short8v a[5], b[4];
        #pragma unroll
        for (int m = 0; m < 5; ++m) {
            u32 off = ((u32)((wr * 80 + m * 16 + rA) * 256 + kk2)) ^ xsw;
            a[m] = *(const short8v*)(lA + off);
        }
        #pragma unroll
        for (int n = 0; n < 4; ++n) {
            u32 off = ((u32)(colv[n] * 256 + kk2)) ^ xsw;
            b[n] = *(const short8v*)(lB + off);
        }
        #pragma unroll
        for (int m = 0; m < 5; ++m)
            #pragma unroll
            for (int n = 0; n < 4; ++n)
                acc[m][n] = MFMA(a[m], b[n], acc[m][n]);
    }

    float csum[4] = {0.f,0.f,0.f,0.f}, csq[4] = {0.f,0.f,0.f,0.f};
    #pragma unroll
    for (int m = 0; m < 5; ++m) {
        int r0 = base + wr * 80 + m * 16 + ((lane >> 4) << 2);
        #pragma unroll
        for (int n = 0; n < 4; ++n) {
            f32x4 d = acc[m][n];
            #pragma unroll
            for (int r = 0; r < 4; ++r) {
                float v = d[r] + bcol[n];
                csum[n] += v; csq[n] += v * v;
                h1u[(size_t)(r0 + r) * 256 + colv[n]] = f2bf(v);
            }
        }
    }
    #pragma unroll
    for (int n = 0; n < 4; ++n) {
        csum[n] += __shfl_xor(csum[n], 16); csum[n] += __shfl_xor(csum[n], 32);
        csq[n]  += __shfl_xor(csq[n], 16);  csq[n]  += __shfl_xor(csq[n], 32);
    }
    if (lane < 16) {
        #pragma unroll
        for (int n = 0; n < 4; ++n) {
            atomicAdd(&slds[colv[n]], csum[n]);
            atomicAdd(&slds[256 + colv[n]], csq[n]);
        }
    }
    __syncthreads();
    atomicAdd(&gstats[tid], slds[tid]);
}

// ---------------- MFMA gemm2: h2 = relu(bn1(h1)) @ W2 + b2 (bf16), stats2 ----------------
__global__ __launch_bounds__(512) void k_gemm2(const u16* __restrict__ h1u,
                                               const char* __restrict__ w2t,
                                               const float* __restrict__ b2,
                                               const float* __restrict__ g1,
                                               const float* __restrict__ beta1,
                                               const float* __restrict__ gstats,
                                               u16* __restrict__ h2b,
                                               float* __restrict__ gstats2) {
    __shared__ u16 Als[160 * 128];    // 40 KB (K half), swizzled
    __shared__ u16 Bls[128 * 256];    // 64 KB swizzled
    __shared__ float a1s[256], b1s[256];
    __shared__ float slds[256];

    const int tid = threadIdx.x, lane = tid & 63, w = tid >> 6;
    const int wr = w >> 2, wc = w & 3;
    const int base = blockIdx.x * 160;

    if (tid < 256) {
        float s = gstats[tid], sq = gstats[256 + tid];
        float mu = s * (1.0f / N_NODES);
        float var = sq * (1.0f / N_NODES) - mu * mu;
        float inv = rsqrtf(var + BN_EPS);
        float a = g1[tid] * inv;
        a1s[tid] = a;
        b1s[tid] = beta1[tid] - mu * a;
        slds[tid] = 0.f;
    }

    char* lA = (char*)Als;
    char* lB = (char*)Bls;
    #pragma unroll
    for (int i = 0; i < 8; ++i)
        gload16(w2t + i * 8192 + w * 1024 + (lane << 4), lB + i * 8192 + w * 1024);

    const int rA = lane & 15;
    const int kb = (lane >> 4) << 3;
    const u32 xsw = ((u32)(rA & 7)) << 4;
    int colv[2]; float bcol[2];
    #pragma unroll
    for (int n = 0; n < 2; ++n) { colv[n] = wc * 32 + n * 16 + rA; bcol[n] = b2[colv[n]]; }

    __syncthreads();   // a1s/b1s ready

    f32x4 acc[5][2];
    #pragma unroll
    for (int m = 0; m < 5; ++m)
        #pragma unroll
        for (int n = 0; n < 2; ++n) acc[m][n] = (f32x4){0.f, 0.f, 0.f, 0.f};

    for (int kh = 0; kh < 2; ++kh) {
        // stage A half-tile with BN1+ReLU applied, swizzled
        #pragma unroll
        for (int i = 0; i < 10; ++i) {
            int id = tid + i * 512;       // 0..5119
            int r = id >> 5;              // 0..159
            int c = id & 31;              // uint2 chunk (4 bf16)
            uint2 v = *(const uint2*)(h1u + (size_t)(base + r) * 256 + kh * 128 + c * 4);
            int cg = kh * 128 + c * 4;
            float4 av = *(const float4*)&a1s[cg];
            float4 bv = *(const float4*)&b1s[cg];
            float f0 = fmaxf(bf2f((u16)v.x)         * av.x + bv.x, 0.f);
            float f1 = fmaxf(bf2f((u16)(v.x >> 16)) * av.y + bv.y, 0.f);
            float f2 = fmaxf(bf2f((u16)v.y)         * av.z + bv.z, 0.f);
            float f3 = fmaxf(bf2f((u16)(v.y >> 16)) * av.w + bv.w, 0.f);
            uint2 p; p.x = pack2(f0, f1); p.y = pack2(f2, f3);
            u32 off = ((u32)(r * 256 + c * 8)) ^ (((u32)(r & 7)) << 4);
            *(uint2*)(lA + off) = p;
        }
        if (kh == 0) asm volatile("s_waitcnt vmcnt(0)" ::: "memory");  // W tile landed
        __syncthreads();

        #pragma unroll
        for (int ks = 0; ks < 4; ++ks) {
            const int kk2 = (ks * 32 + kb) * 2;
            short8v a[5], b[2];
            #pragma unroll
            for (int m = 0; m < 5; ++m) {
                u32 off = ((u32)((wr * 80 + m * 16 + rA) * 256 + kk2)) ^ xsw;
                a[m] = *(const short8v*)(lA + off);
            }
            #pragma unroll
            for (int n = 0; n < 2; ++n) {
                u32 off = ((u32)(colv[n] * 512 + kh * 256 + kk2)) ^ xsw;
                b[n] = *(const short8v*)(lB + off);
            }
            #pragma unroll
            for (int m = 0; m < 5; ++m)
                #pragma unroll
                for (int n = 0; n < 2; ++n)
                    acc[m][n] = MFMA(a[m], b[n], acc[m][n]);
        }
        __syncthreads();   // Als reads done before restage / epilogue
    }

    float csum[2] = {0.f,0.f}, csq[2] = {0.f,0.f};
    #pragma unroll
    for (int m = 0; m < 5; ++m) {
        int r0 = base + wr * 80 + m * 16 + ((lane >> 4) << 2);
        #pragma unroll
        for (int n = 0; n < 2; ++n) {
            f32x4 d = acc[m][n];
            #pragma unroll
            for (int r = 0; r < 4; ++r) {
                float v = d[r] + bcol[n];
                csum[n] += v; csq[n] += v * v;
                h2b[(size_t)(r0 + r) * 128 + colv[n]] = f2bf(v);
            }
        }
    }
    #pragma unroll
    for (int n = 0; n < 2; ++n) {
        csum[n] += __shfl_xor(csum[n], 16); csum[n] += __shfl_xor(csum[n], 32);
        csq[n]  += __shfl_xor(csq[n], 16);  csq[n]  += __shfl_xor(csq[n], 32);
    }
    if (lane < 16) {
        #pragma unroll
        for (int n = 0; n < 2; ++n) {
            atomicAdd(&slds[colv[n]], csum[n]);
            atomicAdd(&slds[128 + colv[n]], csq[n]);
        }
    }
    __syncthreads();
    if (tid < 256) atomicAdd(&gstats2[tid], slds[tid]);
}

// ---------------- out = relu(bn2(h2)) : bf16 in -> f32 out ----------------
__global__ __launch_bounds__(256) void k_bn2(const uint4* __restrict__ h2b4,
                                             float* __restrict__ out,
                                             const float* __restrict__ gstats2,
                                             const float* __restrict__ g2,
                                             const float* __restrict__ beta2) {
    int i = blockIdx.x * 256 + threadIdx.x;      // uint4 index: 100K rows x 16
    const int total = N_NODES * 16;
    if (i >= total) return;
    uint4 v = h2b4[i];
    int c0 = (i & 15) * 8;
    u16 hv[8] = {(u16)v.x, (u16)(v.x >> 16), (u16)v.y, (u16)(v.y >> 16),
                 (u16)v.z, (u16)(v.z >> 16), (u16)v.w, (u16)(v.w >> 16)};
    float res[8];
    #pragma unroll
    for (int j = 0; j < 8; ++j) {
        int c = c0 + j;
        float s = gstats2[c], sq = gstats2[OUT_DIM + c];
        float mu = s * (1.0f / N_NODES);
        float var = sq * (1.0f / N_NODES) - mu * mu;
        float inv = rsqrtf(var + BN_EPS);
        float a = g2[c] * inv;
        float b = beta2[c] - mu * a;
        res[j] = fmaxf(bf2f(hv[j]) * a + b, 0.f);
    }
    ((float4*)out)[i * 2]     = make_float4(res[0], res[1], res[2], res[3]);
    ((float4*)out)[i * 2 + 1] = make_float4(res[4], res[5], res[6], res[7]);
}

extern "C" void kernel_launch(void* const* d_in, const int* in_sizes, int n_in,
                              void* d_out, int out_size, void* d_ws, size_t ws_size,
                              hipStream_t stream) {
    const float* x     = (const float*)d_in[0];
    const int*   ei    = (const int*)d_in[1];
    const float* epsp  = (const float*)d_in[2];
    const float* W1    = (const float*)d_in[3];
    const float* b1    = (const float*)d_in[4];
    const float* g1    = (const float*)d_in[5];
    const float* beta1 = (const float*)d_in[6];
    const float* W2    = (const float*)d_in[7];
    const float* b2    = (const float*)d_in[8];
    const float* g2    = (const float*)d_in[9];
    const float* beta2 = (const float*)d_in[10];

    char* ws = (char*)d_ws;
    char*  aggrb   = ws;                            // [0, 25.6M) bf16 [N][128] pre-swizzled
    u16*   h2b     = (u16*)ws;                      // reuses aggrb region for gemm2 output
    u16*   h1u     = (u16*)(ws + 25600000);         // [25.6M, 76.8M) bf16 [N][256]
    // nxt/head2/xb live INSIDE the h1u region (dead before gemm1 writes it):
    int2*  nxt     = (int2*)(ws + 25600000);        // 12.8 MB (next, src) per edge
    int*   head2   = (int*)(ws + 38400000);         // 800 KB (two parity chains/node)
    uint2* xb      = (uint2*)(ws + 39200000);       // 25.6 MB bf16 [N][128]
    float* gstats  = (float*)(ws + 76800000);       // 512 f32
    float* gstats2 = gstats + 512;                  // 256 f32
    char*  w1t     = ws + 76804096;                 // 64 KB bf16 W1^T swizzled
    char*  w2t     = ws + 76869632;                 // 64 KB bf16 W2^T swizzled
    float* out = (float*)d_out;

    hipMemsetAsync(head2, 0xFF, 800000, stream);    // head = -1
    hipMemsetAsync(gstats, 0, 768 * sizeof(float), stream);

    k_prep<<<12500, 256, 0, stream>>>(x, ei, W1, W2, xb, head2, nxt, w1t, w2t);
    k_aggregate<<<N_NODES / 8, 256, 0, stream>>>((const uint4*)xb, nxt, head2, epsp, aggrb);
    k_gemm1<<<625, 512, 0, stream>>>(aggrb, w1t, b1, h1u, gstats);
    k_gemm2<<<625, 512, 0, stream>>>(h1u, w2t, b2, g1, beta1, gstats, h2b, gstats2);
    k_bn2<<<(N_NODES * 16 + 255) / 256, 256, 0, stream>>>((const uint4*)h2b, out, gstats2, g2, beta2);
}